// Round 20
// baseline (27.861 us; speedup 1.0000x reference)
//
#include <hip/hip_runtime.h>
#include <math.h>

#define HW (1024*1024)
#define BATCH 16

typedef float fx4 __attribute__((ext_vector_type(4)));

// Kernel 1 (v2): split-K x4 parallel params. 768 threads = 192 (b,j) pairs
// x 4 K-chunks of 16. Partial dots -> LDS tree reduce -> mod -> fold.
// Fold: caddmul(clerp(w0,w1,l), s, bias) = w0*s*(1-l) + w1*s*l + bias,
// A = s*(1-l), B = s*l, C = bias.  par: [16][2][6] = {Ar,Ai,Br,Bi,Cr,Ci}
__global__ __launch_bounds__(768) void params_kernel(
    const float* __restrict__ x,       // [16][64]
    const float* __restrict__ W_in,    // [12][64]
    const float* __restrict__ b_in,    // [12]
    const float* __restrict__ W_gate,  // [12][64]
    const float* __restrict__ b_gate,  // [12]
    float* __restrict__ par)           // [16][2][6]
{
    __shared__ float pt[192][4];
    __shared__ float pg[192][4];
    __shared__ float smod[BATCH][12];
    const int t = threadIdx.x;
    const int p = t % 192, k = t / 192;      // pair id, K-chunk
    {
        const int b = p / 12, j = p % 12;
        const float4* x4  = (const float4*)(x + b * 64) + k * 4;
        const float4* wi4 = (const float4*)(W_in + j * 64) + k * 4;
        const float4* wg4 = (const float4*)(W_gate + j * 64) + k * 4;
        float xt = 0.f, xg = 0.f;
#pragma unroll
        for (int q = 0; q < 4; ++q) {
            float4 xv = x4[q], wi = wi4[q], wg = wg4[q];
            xt = fmaf(xv.x, wi.x, xt); xg = fmaf(xv.x, wg.x, xg);
            xt = fmaf(xv.y, wi.y, xt); xg = fmaf(xv.y, wg.y, xg);
            xt = fmaf(xv.z, wi.z, xt); xg = fmaf(xv.z, wg.z, xg);
            xt = fmaf(xv.w, wi.w, xt); xg = fmaf(xv.w, wg.w, xg);
        }
        pt[p][k] = xt;
        pg[p][k] = xg;
    }
    __syncthreads();
    if (t < 192) {
        const int b = t / 12, j = t % 12;
        fx4 vt = *(const fx4*)pt[t];
        fx4 vg = *(const fx4*)pg[t];
        float st = vt[0] + vt[1] + vt[2] + vt[3] + b_in[j];
        float sg = vg[0] + vg[1] + vg[2] + vg[3] + b_gate[j];
        smod[b][j] = st * tanhf(sg);
    }
    __syncthreads();
    if (t < 32) {
        int bb = t >> 1, c = t & 1;
        float l0 = smod[bb][0 + c * 2 + 0] + 0.5f;
        float l1 = smod[bb][0 + c * 2 + 1];
        float br = smod[bb][4 + c * 2 + 0];
        float bi = smod[bb][4 + c * 2 + 1];
        float s0 = smod[bb][8 + c * 2 + 0] + 1.0f;
        float s1 = smod[bb][8 + c * 2 + 1];
        float omr = 1.0f - l0, omi = -l1;      // (1 - l)
        float Ar = s0 * omr - s1 * omi;
        float Ai = s0 * omi + s1 * omr;
        float Br = s0 * l0 - s1 * l1;
        float Bi = s0 * l1 + s1 * l0;
        float* pp = par + (bb * 2 + c) * 6;
        pp[0] = Ar; pp[1] = Ai; pp[2] = Br; pp[3] = Bi; pp[4] = br; pp[5] = bi;
    }
}

// Kernel 2: R18's best main loop verbatim (4 px/thread, nt dwordx4 stores,
// s_load params, no LDS/barrier), with rsqrtf -> raw v_rsq_f32 (absmax-
// neutral per R19).
__global__ __launch_bounds__(256) void main_kernel(
    const float* __restrict__ wts,   // [2][2][HW][2]
    const float* __restrict__ par,   // [16][2][6] = 192 floats
    float* __restrict__ out)         // [16][HW]
{
    const int t = threadIdx.x;
    const int idx = blockIdx.x * 256 + t;    // 0 .. HW/4 - 1 (4 px/thread)
    const float4* w4 = (const float4*)wts;   // [jc][HW/2] float4s

    float4 Wv[4][2];
#pragma unroll
    for (int jc = 0; jc < 4; ++jc) {
        Wv[jc][0] = w4[jc * (HW / 2) + idx * 2 + 0];
        Wv[jc][1] = w4[jc * (HW / 2) + idx * 2 + 1];
    }
    const float* w00 = (const float*)Wv[0];  // j=0, c=0
    const float* w01 = (const float*)Wv[1];  // j=0, c=1
    const float* w10 = (const float*)Wv[2];  // j=1, c=0
    const float* w11 = (const float*)Wv[3];  // j=1, c=1

    fx4* out4 = (fx4*)out;
#pragma unroll
    for (int b = 0; b < BATCH; ++b) {
        // uniform indices -> s_load from constant cache
        const float* p0 = par + (b * 2 + 0) * 6;
        const float* p1 = par + (b * 2 + 1) * 6;
        float A0r = p0[0], A0i = p0[1], B0r = p0[2], B0i = p0[3], c0r = p0[4], c0i = p0[5];
        float A1r = p1[0], A1i = p1[1], B1r = p1[2], B1i = p1[3], c1r = p1[4], c1i = p1[5];

        fx4 o;
#pragma unroll
        for (int p = 0; p < 4; ++p) {
            float a0r = w00[p * 2], a0i = w00[p * 2 + 1];
            float b0r = w10[p * 2], b0i = w10[p * 2 + 1];
            float a1r = w01[p * 2], a1i = w01[p * 2 + 1];
            float b1r = w11[p * 2], b1i = w11[p * 2 + 1];
            float z0r = c0r + A0r * a0r - A0i * a0i + B0r * b0r - B0i * b0i;
            float z0i = c0i + A0r * a0i + A0i * a0r + B0r * b0i + B0i * b0r;
            float z1r = c1r + A1r * a1r - A1i * a1i + B1r * b1r - B1i * b1i;
            float z1i = c1i + A1r * a1i + A1i * a1r + B1r * b1i + B1i * b1r;
            float rs = __builtin_amdgcn_rsqf(z1r * z1r + z1i * z1i + 1e-12f);
            o[p] = (z0r * z1r + z0i * z1i) * rs;
        }
        __builtin_nontemporal_store(o, &out4[b * (HW / 4) + idx]);
    }
}

extern "C" void kernel_launch(void* const* d_in, const int* in_sizes, int n_in,
                              void* d_out, int out_size, void* d_ws, size_t ws_size,
                              hipStream_t stream) {
    const float* x      = (const float*)d_in[0];
    const float* W_in   = (const float*)d_in[1];
    const float* b_in   = (const float*)d_in[2];
    const float* W_gate = (const float*)d_in[3];
    const float* b_gate = (const float*)d_in[4];
    const float* wts    = (const float*)d_in[5];
    float* out = (float*)d_out;
    float* par = (float*)d_ws;

    params_kernel<<<1, 768, 0, stream>>>(x, W_in, b_in, W_gate, b_gate, par);
    main_kernel<<<1024, 256, 0, stream>>>(wts, par, out);
}

// Round 21
// 27.560 us; speedup vs baseline: 1.0109x; 1.0109x over previous
//
#include <hip/hip_runtime.h>
#include <math.h>

#define HW (1024*1024)
#define BATCH 16

typedef float fx4 __attribute__((ext_vector_type(4)));

// FINAL (revert to R18 = best measured 27.13us).
// Kernel 1: per-(batch,channel) complex affine params -> d_ws (768 B).
// Fold: caddmul(clerp(w0,w1,l), s, bias) = w0*s*(1-l) + w1*s*l + bias,
// so A = s*(1-l), B = s*l, C = bias.  par: [16][2][6] = {Ar,Ai,Br,Bi,Cr,Ci}
__global__ __launch_bounds__(192) void params_kernel(
    const float* __restrict__ x,       // [16][64]
    const float* __restrict__ W_in,    // [12][64]
    const float* __restrict__ b_in,    // [12]
    const float* __restrict__ W_gate,  // [12][64]
    const float* __restrict__ b_gate,  // [12]
    float* __restrict__ par)           // [16][2][6]
{
    __shared__ float smod[BATCH][12];
    int t = threadIdx.x;
    int b = t / 12, j = t % 12;
    {
        const float4* x4  = (const float4*)(x + b * 64);
        const float4* wi4 = (const float4*)(W_in + j * 64);
        const float4* wg4 = (const float4*)(W_gate + j * 64);
        float xt = b_in[j], xg = b_gate[j];
#pragma unroll
        for (int k = 0; k < 16; ++k) {
            float4 xv = x4[k], wi = wi4[k], wg = wg4[k];
            xt = fmaf(xv.x, wi.x, xt); xg = fmaf(xv.x, wg.x, xg);
            xt = fmaf(xv.y, wi.y, xt); xg = fmaf(xv.y, wg.y, xg);
            xt = fmaf(xv.z, wi.z, xt); xg = fmaf(xv.z, wg.z, xg);
            xt = fmaf(xv.w, wi.w, xt); xg = fmaf(xv.w, wg.w, xg);
        }
        smod[b][j] = xt * tanhf(xg);
    }
    __syncthreads();
    if (t < 32) {
        int bb = t >> 1, c = t & 1;
        float l0 = smod[bb][0 + c * 2 + 0] + 0.5f;
        float l1 = smod[bb][0 + c * 2 + 1];
        float br = smod[bb][4 + c * 2 + 0];
        float bi = smod[bb][4 + c * 2 + 1];
        float s0 = smod[bb][8 + c * 2 + 0] + 1.0f;
        float s1 = smod[bb][8 + c * 2 + 1];
        float omr = 1.0f - l0, omi = -l1;      // (1 - l)
        float Ar = s0 * omr - s1 * omi;
        float Ai = s0 * omi + s1 * omr;
        float Br = s0 * l0 - s1 * l1;
        float Bi = s0 * l1 + s1 * l0;
        float* p = par + (bb * 2 + c) * 6;
        p[0] = Ar; p[1] = Ai; p[2] = Br; p[3] = Bi; p[4] = br; p[5] = bi;
    }
}

// Kernel 2: streaming transform (R18 best): 4 px/thread, float4 weight
// loads, wave-uniform s_load params (no LDS, no barrier), NONTEMPORAL
// dwordx4 stores (bypass L2 write-allocate; -1.4us proven in R18 A/B).
__global__ __launch_bounds__(256) void main_kernel(
    const float* __restrict__ wts,   // [2][2][HW][2]
    const float* __restrict__ par,   // [16][2][6] = 192 floats
    float* __restrict__ out)         // [16][HW]
{
    const int t = threadIdx.x;
    const int idx = blockIdx.x * 256 + t;    // 0 .. HW/4 - 1 (4 px/thread)
    const float4* w4 = (const float4*)wts;   // [jc][HW/2] float4s

    float4 Wv[4][2];
#pragma unroll
    for (int jc = 0; jc < 4; ++jc) {
        Wv[jc][0] = w4[jc * (HW / 2) + idx * 2 + 0];
        Wv[jc][1] = w4[jc * (HW / 2) + idx * 2 + 1];
    }
    const float* w00 = (const float*)Wv[0];  // j=0, c=0
    const float* w01 = (const float*)Wv[1];  // j=0, c=1
    const float* w10 = (const float*)Wv[2];  // j=1, c=0
    const float* w11 = (const float*)Wv[3];  // j=1, c=1

    fx4* out4 = (fx4*)out;
#pragma unroll
    for (int b = 0; b < BATCH; ++b) {
        // uniform indices (no threadIdx) -> s_load from constant cache
        const float* p0 = par + (b * 2 + 0) * 6;
        const float* p1 = par + (b * 2 + 1) * 6;
        float A0r = p0[0], A0i = p0[1], B0r = p0[2], B0i = p0[3], c0r = p0[4], c0i = p0[5];
        float A1r = p1[0], A1i = p1[1], B1r = p1[2], B1i = p1[3], c1r = p1[4], c1i = p1[5];

        fx4 o;
#pragma unroll
        for (int p = 0; p < 4; ++p) {
            float a0r = w00[p * 2], a0i = w00[p * 2 + 1];
            float b0r = w10[p * 2], b0i = w10[p * 2 + 1];
            float a1r = w01[p * 2], a1i = w01[p * 2 + 1];
            float b1r = w11[p * 2], b1i = w11[p * 2 + 1];
            float z0r = c0r + A0r * a0r - A0i * a0i + B0r * b0r - B0i * b0i;
            float z0i = c0i + A0r * a0i + A0i * a0r + B0r * b0i + B0i * b0r;
            float z1r = c1r + A1r * a1r - A1i * a1i + B1r * b1r - B1i * b1i;
            float z1i = c1i + A1r * a1i + A1i * a1r + B1r * b1i + B1i * b1r;
            float rs = rsqrtf(z1r * z1r + z1i * z1i + 1e-12f);
            o[p] = (z0r * z1r + z0i * z1i) * rs;
        }
        __builtin_nontemporal_store(o, &out4[b * (HW / 4) + idx]);
    }
}

extern "C" void kernel_launch(void* const* d_in, const int* in_sizes, int n_in,
                              void* d_out, int out_size, void* d_ws, size_t ws_size,
                              hipStream_t stream) {
    const float* x      = (const float*)d_in[0];
    const float* W_in   = (const float*)d_in[1];
    const float* b_in   = (const float*)d_in[2];
    const float* W_gate = (const float*)d_in[3];
    const float* b_gate = (const float*)d_in[4];
    const float* wts    = (const float*)d_in[5];
    float* out = (float*)d_out;
    float* par = (float*)d_ws;

    params_kernel<<<1, 192, 0, stream>>>(x, W_in, b_in, W_gate, b_gate, par);
    main_kernel<<<1024, 256, 0, stream>>>(wts, par, out);
}